// Round 3
// baseline (766.612 us; speedup 1.0000x reference)
//
#include <hip/hip_runtime.h>

#define DIM 160
#define SLICE (DIM * DIM)
#define TH 16
#define TW 16
#define CD 40   // output slices per block chunk; 160/CD = 4 chunks per batch

// Fused LNCC, separable h -> w -> d. Rounds 0-2 showed the kernel is
// LDS-pipe-bound (~85-90% busy by op-count model), so this version moves the
// halo staging + h-sum tap reads OFF the LDS pipe: no S buffer at all.
// Per input slice z (48 per chunk), 2 phases / 2 barriers:
//   P1: wave0 lanes 0..47 (one (w-group ja, row-pair rp) each) write the
//       5-channel h-sums S0/S1 (computed last P2, in registers) to T (10 b128).
//       All 256 threads run stage C for slice z-1: read U, update the 9-deep
//       register d-ring (compile-time phase via 9-unrolled loop), emit ncc.
//   P2: wave1 does the 9-tap w-sum T->U (b128 slide, 20 ops). wave0 loads the
//       10 h-tap rows of x,y for slice z+1 DIRECTLY FROM GLOBAL (L1-resident:
//       ~4.6KB/slice working set, 9x tap re-read hits L1, not the LDS pipe),
//       accumulating 5-channel h-sums in registers (2-row slide).
// LDS per slice: 10 + 20 b128 + 20 b32 wave-ops (was ~73 b128 + 20 b32).
// T row stride 28 (mod 32 = 28): stage-B reads 2-way/free; stride 24 was the
// round-2 conflict regression (i*24 = 0 mod 32 for all row-quads).
// w-edge clamp: halo float4 groups are either fully in-bounds or fully
// clamped to one edge element (TW=16, halo=4) -> single splat load.
#define TIDX(c,i,j) ((c)*448 + (i)*28 + (j))   // T: 16x28 plane (24 cols + 4 pad)
#define UIDX(c,i,j) ((c)*260 + (i)*16 + (j))   // U: 16x16 plane (+4 pad)

__global__ __launch_bounds__(256, 3)
void lncc_kernel(const float* __restrict__ x, const float* __restrict__ y,
                 float* __restrict__ out)
{
    __shared__ __align__(16) float T[5 * 448];
    __shared__ __align__(16) float U[5 * 260];
    __shared__ float wsum[4];

    const int t  = threadIdx.x;
    const int w0 = blockIdx.x * TW;
    const int h0 = blockIdx.y * TH;
    const int bz = blockIdx.z;
    const int b   = bz >> 2;              // batch
    const int zo0 = (bz & 3) * CD;        // first output slice of chunk

    const float* xb = x + (size_t)b * (DIM * SLICE);
    const float* yb = y + (size_t)b * (DIM * SLICE);

    // ---- stage A role (t<48): (w-group ja, row-pair rp) ----
    const int ja = t % 6;                 // 0..5
    const int rp = t / 6;                 // 0..7
    const int r0 = rp * 2;                // output rows r0, r0+1
    const int gwb = w0 - 4 + 4 * ja;
    const bool fastw = (gwb >= 0) && (gwb + 3 < DIM);
    const int jsp = (gwb < 0) ? 0 : (DIM - 1);   // splat index when clamped
    int ghoff[10];                        // tap row offsets: fixed across z
    #pragma unroll
    for (int k = 0; k < 10; ++k) {
        int gh = h0 + r0 - 4 + k;
        gh = min(max(gh, 0), DIM - 1);
        ghoff[k] = gh * DIM;
    }

    // ---- stage B role (wave1): (row i3, w-group j3) ----
    const int tb = t - 64;
    const int i3 = tb >> 2;               // 0..15
    const int j3 = (tb & 3) * 4;          // 0,4,8,12

    // ---- stage C role: one output column each ----
    const int i4 = t >> 4;
    const int j4 = t & 15;

    float hist[9][5];                     // register ring (constant indices)
    float rs[5] = {0.f, 0.f, 0.f, 0.f, 0.f};
    float acc = 0.f;
    float4 S0[5], S1[5];                  // h-sums carried P2 -> next P1

    auto loadrow = [&](const float* sl, int k) -> float4 {
        const float* row = sl + ghoff[k];
        if (fastw) return *reinterpret_cast<const float4*>(row + gwb);
        const float v = row[jsp];
        return make_float4(v, v, v, v);
    };

    // load 10 taps of x,y for slice zsl, fold into 5-channel h-sums for rows
    // r0 (taps 0..8) and r0+1 (slide: +tap9 -tap0). Two 5-tap batches cap
    // in-flight loads at 10 b128 to limit VGPR pressure.
    auto taps_accumulate = [&](int zsl) {
        const float* xs = xb + (size_t)zsl * SLICE;
        const float* ys = yb + (size_t)zsl * SLICE;
        float4 sx = make_float4(0,0,0,0), sy = sx, sxx = sx, syy = sx, sxy = sx;
        float4 x0, y0, x9, y9;
        {
            float4 tx[5], ty[5];
            #pragma unroll
            for (int k = 0; k < 5; ++k) { tx[k] = loadrow(xs, k); ty[k] = loadrow(ys, k); }
            x0 = tx[0]; y0 = ty[0];
            #pragma unroll
            for (int k = 0; k < 5; ++k) {
                sx += tx[k]; sy += ty[k];
                sxx += tx[k] * tx[k]; syy += ty[k] * ty[k]; sxy += tx[k] * ty[k];
            }
        }
        {
            float4 tx[5], ty[5];
            #pragma unroll
            for (int k = 0; k < 5; ++k) { tx[k] = loadrow(xs, 5 + k); ty[k] = loadrow(ys, 5 + k); }
            x9 = tx[4]; y9 = ty[4];
            #pragma unroll
            for (int k = 0; k < 4; ++k) {
                sx += tx[k]; sy += ty[k];
                sxx += tx[k] * tx[k]; syy += ty[k] * ty[k]; sxy += tx[k] * ty[k];
            }
        }
        S0[0] = sx;  S0[1] = sy;  S0[2] = sxx; S0[3] = syy; S0[4] = sxy;
        S1[0] = sx  + x9 - x0;
        S1[1] = sy  + y9 - y0;
        S1[2] = sxx + x9 * x9 - x0 * x0;
        S1[3] = syy + y9 * y9 - y0 * y0;
        S1[4] = sxy + x9 * y9 - x0 * y0;
    };

    const int zfirst = zo0 - 4;           // 48 input slices: zfirst .. zfirst+47
    if (t < 48) taps_accumulate(max(zfirst, 0));

    // iteration s: P1 writes T(slice s) + stage C(slice s-1); P2 w-sums
    // slice s (T->U) + loads/accumulates taps for slice s+1. 49 iterations
    // (s=48 is the C-only epilogue). 9-unroll keeps ring phase compile-time.
    for (int base = 0; base < 54; base += 9) {
        #pragma unroll
        for (int p = 0; p < 9; ++p) {
            const int s = base + p;
            if (s <= 48) {
                // ---- P1 ----
                if (s <= 47 && t < 48) {
                    #pragma unroll
                    for (int c = 0; c < 5; ++c) {
                        *reinterpret_cast<float4*>(&T[TIDX(c, r0,     4 * ja)]) = S0[c];
                        *reinterpret_cast<float4*>(&T[TIDX(c, r0 + 1, 4 * ja)]) = S1[c];
                    }
                }
                if (s >= 1) {             // stage C for slice s-1
                    const int cp = (p + 8) % 9;   // (s-1) mod 9, compile-time
                    float u[5];
                    #pragma unroll
                    for (int c = 0; c < 5; ++c) {
                        u[c] = U[UIDX(c, i4, j4)];
                        rs[c] += u[c];
                        hist[cp][c] = u[c];
                    }
                    if (s >= 9) {
                        const float inv = 1.0f / 729.0f;
                        const float xm = rs[0] * inv, ym = rs[1] * inv;
                        const float x2 = rs[2] * inv, y2 = rs[3] * inv;
                        const float xy = rs[4] * inv;
                        const float cross = xy - xm * ym;
                        const float vx = x2 - xm * xm;
                        const float vy = y2 - ym * ym;
                        acc += cross * cross / (vx * vy + 1e-5f);
                        const int po = (cp + 1) % 9;  // slice leaving the window
                        #pragma unroll
                        for (int c = 0; c < 5; ++c)
                            rs[c] -= hist[po][c];
                    }
                }
                __syncthreads();
                // ---- P2 ----
                if (s <= 47 && tb >= 0 && tb < 64) {   // stage B: w-sum T->U
                    #pragma unroll
                    for (int c = 0; c < 5; ++c) {
                        const float4 t0 = *reinterpret_cast<const float4*>(&T[TIDX(c, i3, j3)]);
                        const float4 t1 = *reinterpret_cast<const float4*>(&T[TIDX(c, i3, j3 + 4)]);
                        const float4 t2 = *reinterpret_cast<const float4*>(&T[TIDX(c, i3, j3 + 8)]);
                        float4 uo;
                        float sv = t0.x + t0.y + t0.z + t0.w
                                 + t1.x + t1.y + t1.z + t1.w + t2.x;
                        uo.x = sv;
                        sv += t2.y - t0.x; uo.y = sv;
                        sv += t2.z - t0.y; uo.z = sv;
                        sv += t2.w - t0.z; uo.w = sv;
                        *reinterpret_cast<float4*>(&U[UIDX(c, i3, j3)]) = uo;
                    }
                }
                if (s <= 46 && t < 48) {  // taps for slice s+1 (used next P1)
                    const int zn = min(max(zfirst + s + 1, 0), DIM - 1);
                    taps_accumulate(zn);
                }
                __syncthreads();
            }
        }
    }

    // ---- block reduction: wave shuffle, then 4 partials via LDS ----
    #pragma unroll
    for (int off = 32; off > 0; off >>= 1)
        acc += __shfl_down(acc, off, 64);
    const int wave = t >> 6;
    if ((t & 63) == 0) wsum[wave] = acc;
    __syncthreads();
    if (t == 0) {
        const float s = wsum[0] + wsum[1] + wsum[2] + wsum[3];
        atomicAdd(out, -s * (1.0f / 8192000.0f));
    }
}

extern "C" void kernel_launch(void* const* d_in, const int* in_sizes, int n_in,
                              void* d_out, int out_size, void* d_ws, size_t ws_size,
                              hipStream_t stream)
{
    const float* x = (const float*)d_in[0];
    const float* y = (const float*)d_in[1];
    float* out = (float*)d_out;

    // d_out is poisoned 0xAA before every call; accumulate atomically on zero
    hipMemsetAsync(out, 0, sizeof(float), stream);

    dim3 grid(DIM / TW, DIM / TH, 2 * (DIM / CD));  // 10 x 10 x 8 = 800 blocks
    lncc_kernel<<<grid, 256, 0, stream>>>(x, y, out);
}

// Round 4
// 166.545 us; speedup vs baseline: 4.6030x; 4.6030x over previous
//
#include <hip/hip_runtime.h>

#define DIM 160
#define SLICE (DIM * DIM)
#define TH 16
#define TW 16
#define CD 40   // output slices per block chunk; 160/CD = 4 chunks per batch

// Fused LNCC, separable w -> h -> d. Round 0-2 established the kernel is
// LDS-pipe-bound (~85-90% busy by wave-op model); round 3 showed the fix
// (fewer LDS ops) dies if register pressure spills (WRITE_SIZE 200MB).
// This version: w-sum in REGISTERS at load time (VMEM pipe was 77% idle),
// h-sum via one small LDS round trip, z-sum in the proven register ring.
// Per input slice z (48 per chunk), 2 barriers:
//   Phase A: all 256 threads ring-update from U(z-1) (5 b32 reads);
//            loader threads t>=160 (96 = 24 halo rows x 4 col-quads) compute
//            5-channel w-sums from float4s loaded LAST phase B (named scalars
//            only, 24 VGPR carried) and write H (10 b128 wave-issues).
//   Phase B: wave0 lanes t<40 (5ch x 4quad x 2half) h-sum H->U via register
//            slide (16 read + 8 write b128); loaders issue next slice's
//            6 float4 global loads (consumed next phase A, 1-barrier hide).
// LDS ops/slice: 34 b128 + 20 b32 (round 0: ~73 b128 + 20 b32). Lane maps
// mirror round-0's measured-cheap patterns (adjacent lanes contiguous 16B).
#define HIDX(c,i,j) ((c)*680 + (i)*28 + (j))   // H: 24x28 plane (16 used + pad)
#define UIDX(c,i,j) ((c)*260 + (i)*16 + (j))   // U: 16x16 plane (+4 pad)

// 9-tap sliding window over 12 consecutive values -> 4 outputs
#define WSLIDE(dst, V0,V1,V2,V3,V4,V5,V6,V7,V8,V9,V10,V11) do {            \
    float s_ = (V0)+(V1)+(V2)+(V3)+(V4)+(V5)+(V6)+(V7)+(V8);               \
    float4 o_; o_.x = s_;                                                  \
    s_ += (V9)  - (V0); o_.y = s_;                                         \
    s_ += (V10) - (V1); o_.z = s_;                                         \
    s_ += (V11) - (V2); o_.w = s_;                                         \
    (dst) = o_; } while (0)

__global__ __launch_bounds__(256, 2)
void lncc_kernel(const float* __restrict__ x, const float* __restrict__ y,
                 float* __restrict__ out)
{
    __shared__ __align__(16) float H[5 * 680];
    __shared__ __align__(16) float U[5 * 260];
    __shared__ float wsum[4];

    const int t  = threadIdx.x;
    const int w0 = blockIdx.x * TW;
    const int h0 = blockIdx.y * TH;
    const int bz = blockIdx.z;
    const int b   = bz >> 2;              // batch
    const int zo0 = (bz & 3) * CD;        // first output slice of chunk

    const float* xb = x + (size_t)b * (DIM * SLICE);
    const float* yb = y + (size_t)b * (DIM * SLICE);

    // ---- loader role (t in [160,256)): (halo row lrw, output col-quad lq) ----
    const int lt  = t - 160;              // 0..95
    const int lrw = lt >> 2;              // 0..23
    const int lq  = lt & 3;               // 0..3
    const int ghr = min(max(h0 - 4 + lrw, 0), DIM - 1);
    const int rowoff = ghr * DIM;
    const int gws = w0 + 4 * lq - 4;      // first of 12 input cols (aligned)
    // quad 1 (cols gws+4..gws+7) is always in-bounds; quads 0/2 clamp at edges
    const bool ok0 = (gws >= 0);
    const bool ok2 = (gws + 8 <= DIM - 4);
    const int jj = 4 * lq;

    // ---- h-sum role (t < 40): (channel hcc, col-quad hq, row-half hh) ----
    const int hcc = t >> 3;               // 0..4
    const int hq  = (t >> 1) & 3;         // 0..3
    const int hh  = t & 1;                // 0..1
    const int hr0 = hh * 8;
    const int hjj = 4 * hq;

    // ---- ring role: one output column each ----
    const int i4 = t >> 4;
    const int j4 = t & 15;

    float hist[9][5];                     // register ring (constant indices)
    float rs[5] = {0.f, 0.f, 0.f, 0.f, 0.f};
    float acc = 0.f;

    // carried loads (24 VGPR): 12 cols of x,y for this thread's quad-row
    float4 lx0, lx1, lx2, ly0, ly1, ly2;

    auto issue_loads = [&](int zsl) {
        const float* xs = xb + (size_t)zsl * SLICE + rowoff;
        const float* ys = yb + (size_t)zsl * SLICE + rowoff;
        lx1 = *reinterpret_cast<const float4*>(xs + gws + 4);
        ly1 = *reinterpret_cast<const float4*>(ys + gws + 4);
        if (ok0) {
            lx0 = *reinterpret_cast<const float4*>(xs + gws);
            ly0 = *reinterpret_cast<const float4*>(ys + gws);
        } else {
            const float v = xs[0];       lx0 = make_float4(v, v, v, v);
            const float w = ys[0];       ly0 = make_float4(w, w, w, w);
        }
        if (ok2) {
            lx2 = *reinterpret_cast<const float4*>(xs + gws + 8);
            ly2 = *reinterpret_cast<const float4*>(ys + gws + 8);
        } else {
            const float v = xs[DIM - 1]; lx2 = make_float4(v, v, v, v);
            const float w = ys[DIM - 1]; ly2 = make_float4(w, w, w, w);
        }
    };

    const int zfirst = zo0 - 4;           // 48 input slices: zfirst .. zfirst+47
    if (t >= 160) issue_loads(max(zfirst, 0));

    // iteration s: A = ring(slice s-1 via U) + w-sum/write H(slice s);
    //              B = h-sum H(s)->U(s) + issue loads for slice s+1.
    // s = 48 is the ring-only epilogue. 9-unroll keeps ring phase compile-time.
    for (int base = 0; base < 54; base += 9) {
        #pragma unroll
        for (int p = 0; p < 9; ++p) {
            const int s = base + p;
            if (s <= 48) {
                // ---- Phase A ----
                if (s >= 1) {             // ring for slice s-1 (reads U(s-1))
                    const int cp = (p + 8) % 9;   // (s-1) mod 9, compile-time
                    float u[5];
                    #pragma unroll
                    for (int c = 0; c < 5; ++c) {
                        u[c] = U[UIDX(c, i4, j4)];
                        rs[c] += u[c];
                        hist[cp][c] = u[c];
                    }
                    if (s >= 9) {
                        const float inv = 1.0f / 729.0f;
                        const float xm = rs[0] * inv, ym = rs[1] * inv;
                        const float x2 = rs[2] * inv, y2 = rs[3] * inv;
                        const float xy = rs[4] * inv;
                        const float cross = xy - xm * ym;
                        const float vx = x2 - xm * xm;
                        const float vy = y2 - ym * ym;
                        acc += cross * cross / (vx * vy + 1e-5f);
                        const int po = (cp + 1) % 9;  // slice leaving window
                        #pragma unroll
                        for (int c = 0; c < 5; ++c)
                            rs[c] -= hist[po][c];
                    }
                }
                if (s <= 47 && t >= 160) {   // w-sums of carried loads -> H
                    float4 o;
                    WSLIDE(o, lx0.x,lx0.y,lx0.z,lx0.w, lx1.x,lx1.y,lx1.z,lx1.w,
                              lx2.x,lx2.y,lx2.z,lx2.w);
                    *reinterpret_cast<float4*>(&H[HIDX(0, lrw, jj)]) = o;
                    WSLIDE(o, ly0.x,ly0.y,ly0.z,ly0.w, ly1.x,ly1.y,ly1.z,ly1.w,
                              ly2.x,ly2.y,ly2.z,ly2.w);
                    *reinterpret_cast<float4*>(&H[HIDX(1, lrw, jj)]) = o;
                    float4 a0 = lx0 * lx0, a1 = lx1 * lx1, a2 = lx2 * lx2;
                    WSLIDE(o, a0.x,a0.y,a0.z,a0.w, a1.x,a1.y,a1.z,a1.w,
                              a2.x,a2.y,a2.z,a2.w);
                    *reinterpret_cast<float4*>(&H[HIDX(2, lrw, jj)]) = o;
                    a0 = ly0 * ly0; a1 = ly1 * ly1; a2 = ly2 * ly2;
                    WSLIDE(o, a0.x,a0.y,a0.z,a0.w, a1.x,a1.y,a1.z,a1.w,
                              a2.x,a2.y,a2.z,a2.w);
                    *reinterpret_cast<float4*>(&H[HIDX(3, lrw, jj)]) = o;
                    a0 = lx0 * ly0; a1 = lx1 * ly1; a2 = lx2 * ly2;
                    WSLIDE(o, a0.x,a0.y,a0.z,a0.w, a1.x,a1.y,a1.z,a1.w,
                              a2.x,a2.y,a2.z,a2.w);
                    *reinterpret_cast<float4*>(&H[HIDX(4, lrw, jj)]) = o;
                }
                __syncthreads();
                // ---- Phase B ----
                if (s <= 47 && t < 40) {     // h-sum H(s) -> U(s), reg slide
                    float4 sum = make_float4(0.f, 0.f, 0.f, 0.f);
                    #pragma unroll
                    for (int k = 0; k < 9; ++k)
                        sum += *reinterpret_cast<const float4*>(&H[HIDX(hcc, hr0 + k, hjj)]);
                    *reinterpret_cast<float4*>(&U[UIDX(hcc, hr0, hjj)]) = sum;
                    #pragma unroll
                    for (int m = 1; m < 8; ++m) {
                        sum += *reinterpret_cast<const float4*>(&H[HIDX(hcc, hr0 + m + 8, hjj)])
                             - *reinterpret_cast<const float4*>(&H[HIDX(hcc, hr0 + m - 1, hjj)]);
                        *reinterpret_cast<float4*>(&U[UIDX(hcc, hr0 + m, hjj)]) = sum;
                    }
                }
                if (s <= 46 && t >= 160)     // loads for slice s+1 (next A)
                    issue_loads(min(max(zfirst + s + 1, 0), DIM - 1));
                __syncthreads();
            }
        }
    }

    // ---- block reduction: wave shuffle, then 4 partials via LDS ----
    #pragma unroll
    for (int off = 32; off > 0; off >>= 1)
        acc += __shfl_down(acc, off, 64);
    const int wave = t >> 6;
    if ((t & 63) == 0) wsum[wave] = acc;
    __syncthreads();
    if (t == 0) {
        const float s = wsum[0] + wsum[1] + wsum[2] + wsum[3];
        atomicAdd(out, -s * (1.0f / 8192000.0f));
    }
}

extern "C" void kernel_launch(void* const* d_in, const int* in_sizes, int n_in,
                              void* d_out, int out_size, void* d_ws, size_t ws_size,
                              hipStream_t stream)
{
    const float* x = (const float*)d_in[0];
    const float* y = (const float*)d_in[1];
    float* out = (float*)d_out;

    // d_out is poisoned 0xAA before every call; accumulate atomically on zero
    hipMemsetAsync(out, 0, sizeof(float), stream);

    dim3 grid(DIM / TW, DIM / TH, 2 * (DIM / CD));  // 10 x 10 x 8 = 800 blocks
    lncc_kernel<<<grid, 256, 0, stream>>>(x, y, out);
}

// Round 5
// 165.172 us; speedup vs baseline: 4.6413x; 1.0083x over previous
//
#include <hip/hip_runtime.h>

#define DIM 160
#define SLICE (DIM * DIM)
#define TH 16
#define TW 16
#define CD 40   // output slices per block chunk; 160/CD = 4 chunks per batch

// Fused LNCC, separable w -> h -> d. History:
//  R0-R2: 3-barrier LDS pipeline, LDS-pipe-bound (~83-91% busy by op model).
//  R4: w-sum moved to registers at load time (LDS ops/slice ~93 -> ~54),
//      but time stayed ~97us: all pipes <45% busy -> latency-bound. Culprit:
//      __syncthreads drains vmcnt(0), so the 6 global loads/loader issued at
//      the END of phase B stall every slice for a full HBM/L2 latency.
//  This version: identical structure, but in-loop barriers are RAW s_barrier
//  with only lgkmcnt(0) (LDS visibility). Global loads stay in flight across
//  the barrier (T4 counted-vmcnt pattern); the only vmcnt wait is the
//  compiler's auto-wait before first use next phase A, covered by ~500-800cy
//  of ring + h-sum work.
// Per input slice z (48 per chunk), 2 barriers:
//   Phase A: all 256 threads ring-update from U(z-1) (5 b32 reads);
//            loader threads t>=160 (96 = 24 halo rows x 4 col-quads) compute
//            5-channel w-sums from float4s loaded LAST phase B (named scalars
//            only, 24 VGPR carried) and write H (10 b128 wave-issues).
//   Phase B: wave0 lanes t<40 (5ch x 4quad x 2half) h-sum H->U via register
//            slide (16 read + 8 write b128); loaders issue next slice's
//            6 float4 global loads (in flight across the barrier).
#define HIDX(c,i,j) ((c)*680 + (i)*28 + (j))   // H: 24x28 plane (16 used + pad)
#define UIDX(c,i,j) ((c)*260 + (i)*16 + (j))   // U: 16x16 plane (+4 pad)

// 9-tap sliding window over 12 consecutive values -> 4 outputs
#define WSLIDE(dst, V0,V1,V2,V3,V4,V5,V6,V7,V8,V9,V10,V11) do {            \
    float s_ = (V0)+(V1)+(V2)+(V3)+(V4)+(V5)+(V6)+(V7)+(V8);               \
    float4 o_; o_.x = s_;                                                  \
    s_ += (V9)  - (V0); o_.y = s_;                                         \
    s_ += (V10) - (V1); o_.z = s_;                                         \
    s_ += (V11) - (V2); o_.w = s_;                                         \
    (dst) = o_; } while (0)

// Barrier that does NOT drain vmcnt: LDS producers/consumers are ordered by
// lgkmcnt(0); global loads issued before it stay in flight (HK T4 pattern).
// "memory" clobbers pin LDS ops on both sides of the barrier.
static __device__ __forceinline__ void barrier_novm()
{
    asm volatile("s_waitcnt lgkmcnt(0)" ::: "memory");
    __builtin_amdgcn_s_barrier();
    asm volatile("" ::: "memory");
}

__global__ __launch_bounds__(256, 2)
void lncc_kernel(const float* __restrict__ x, const float* __restrict__ y,
                 float* __restrict__ out)
{
    __shared__ __align__(16) float H[5 * 680];
    __shared__ __align__(16) float U[5 * 260];
    __shared__ float wsum[4];

    const int t  = threadIdx.x;
    const int w0 = blockIdx.x * TW;
    const int h0 = blockIdx.y * TH;
    const int bz = blockIdx.z;
    const int b   = bz >> 2;              // batch
    const int zo0 = (bz & 3) * CD;        // first output slice of chunk

    const float* xb = x + (size_t)b * (DIM * SLICE);
    const float* yb = y + (size_t)b * (DIM * SLICE);

    // ---- loader role (t in [160,256)): (halo row lrw, output col-quad lq) ----
    const int lt  = t - 160;              // 0..95
    const int lrw = lt >> 2;              // 0..23
    const int lq  = lt & 3;               // 0..3
    const int ghr = min(max(h0 - 4 + lrw, 0), DIM - 1);
    const int rowoff = ghr * DIM;
    const int gws = w0 + 4 * lq - 4;      // first of 12 input cols (aligned)
    // quad 1 (cols gws+4..gws+7) is always in-bounds; quads 0/2 clamp at edges
    const bool ok0 = (gws >= 0);
    const bool ok2 = (gws + 8 <= DIM - 4);
    const int jj = 4 * lq;

    // ---- h-sum role (t < 40): (channel hcc, col-quad hq, row-half hh) ----
    const int hcc = t >> 3;               // 0..4
    const int hq  = (t >> 1) & 3;         // 0..3
    const int hh  = t & 1;                // 0..1
    const int hr0 = hh * 8;
    const int hjj = 4 * hq;

    // ---- ring role: one output column each ----
    const int i4 = t >> 4;
    const int j4 = t & 15;

    float hist[9][5];                     // register ring (constant indices)
    float rs[5] = {0.f, 0.f, 0.f, 0.f, 0.f};
    float acc = 0.f;

    // carried loads (24 VGPR): 12 cols of x,y for this thread's quad-row
    float4 lx0, lx1, lx2, ly0, ly1, ly2;

    auto issue_loads = [&](int zsl) {
        const float* xs = xb + (size_t)zsl * SLICE + rowoff;
        const float* ys = yb + (size_t)zsl * SLICE + rowoff;
        lx1 = *reinterpret_cast<const float4*>(xs + gws + 4);
        ly1 = *reinterpret_cast<const float4*>(ys + gws + 4);
        if (ok0) {
            lx0 = *reinterpret_cast<const float4*>(xs + gws);
            ly0 = *reinterpret_cast<const float4*>(ys + gws);
        } else {
            const float v = xs[0];       lx0 = make_float4(v, v, v, v);
            const float w = ys[0];       ly0 = make_float4(w, w, w, w);
        }
        if (ok2) {
            lx2 = *reinterpret_cast<const float4*>(xs + gws + 8);
            ly2 = *reinterpret_cast<const float4*>(ys + gws + 8);
        } else {
            const float v = xs[DIM - 1]; lx2 = make_float4(v, v, v, v);
            const float w = ys[DIM - 1]; ly2 = make_float4(w, w, w, w);
        }
    };

    const int zfirst = zo0 - 4;           // 48 input slices: zfirst .. zfirst+47
    if (t >= 160) issue_loads(max(zfirst, 0));

    // iteration s: A = ring(slice s-1 via U) + w-sum/write H(slice s);
    //              B = h-sum H(s)->U(s) + issue loads for slice s+1.
    // s = 48 is the ring-only epilogue. 9-unroll keeps ring phase compile-time.
    for (int base = 0; base < 54; base += 9) {
        #pragma unroll
        for (int p = 0; p < 9; ++p) {
            const int s = base + p;
            if (s <= 48) {
                // ---- Phase A ----
                if (s >= 1) {             // ring for slice s-1 (reads U(s-1))
                    const int cp = (p + 8) % 9;   // (s-1) mod 9, compile-time
                    float u[5];
                    #pragma unroll
                    for (int c = 0; c < 5; ++c) {
                        u[c] = U[UIDX(c, i4, j4)];
                        rs[c] += u[c];
                        hist[cp][c] = u[c];
                    }
                    if (s >= 9) {
                        const float inv = 1.0f / 729.0f;
                        const float xm = rs[0] * inv, ym = rs[1] * inv;
                        const float x2 = rs[2] * inv, y2 = rs[3] * inv;
                        const float xy = rs[4] * inv;
                        const float cross = xy - xm * ym;
                        const float vx = x2 - xm * xm;
                        const float vy = y2 - ym * ym;
                        acc += cross * cross / (vx * vy + 1e-5f);
                        const int po = (cp + 1) % 9;  // slice leaving window
                        #pragma unroll
                        for (int c = 0; c < 5; ++c)
                            rs[c] -= hist[po][c];
                    }
                }
                if (s <= 47 && t >= 160) {   // w-sums of carried loads -> H
                    float4 o;
                    WSLIDE(o, lx0.x,lx0.y,lx0.z,lx0.w, lx1.x,lx1.y,lx1.z,lx1.w,
                              lx2.x,lx2.y,lx2.z,lx2.w);
                    *reinterpret_cast<float4*>(&H[HIDX(0, lrw, jj)]) = o;
                    WSLIDE(o, ly0.x,ly0.y,ly0.z,ly0.w, ly1.x,ly1.y,ly1.z,ly1.w,
                              ly2.x,ly2.y,ly2.z,ly2.w);
                    *reinterpret_cast<float4*>(&H[HIDX(1, lrw, jj)]) = o;
                    float4 a0 = lx0 * lx0, a1 = lx1 * lx1, a2 = lx2 * lx2;
                    WSLIDE(o, a0.x,a0.y,a0.z,a0.w, a1.x,a1.y,a1.z,a1.w,
                              a2.x,a2.y,a2.z,a2.w);
                    *reinterpret_cast<float4*>(&H[HIDX(2, lrw, jj)]) = o;
                    a0 = ly0 * ly0; a1 = ly1 * ly1; a2 = ly2 * ly2;
                    WSLIDE(o, a0.x,a0.y,a0.z,a0.w, a1.x,a1.y,a1.z,a1.w,
                              a2.x,a2.y,a2.z,a2.w);
                    *reinterpret_cast<float4*>(&H[HIDX(3, lrw, jj)]) = o;
                    a0 = lx0 * ly0; a1 = lx1 * ly1; a2 = lx2 * ly2;
                    WSLIDE(o, a0.x,a0.y,a0.z,a0.w, a1.x,a1.y,a1.z,a1.w,
                              a2.x,a2.y,a2.z,a2.w);
                    *reinterpret_cast<float4*>(&H[HIDX(4, lrw, jj)]) = o;
                }
                barrier_novm();
                // ---- Phase B ----
                if (s <= 47 && t < 40) {     // h-sum H(s) -> U(s), reg slide
                    float4 sum = make_float4(0.f, 0.f, 0.f, 0.f);
                    #pragma unroll
                    for (int k = 0; k < 9; ++k)
                        sum += *reinterpret_cast<const float4*>(&H[HIDX(hcc, hr0 + k, hjj)]);
                    *reinterpret_cast<float4*>(&U[UIDX(hcc, hr0, hjj)]) = sum;
                    #pragma unroll
                    for (int m = 1; m < 8; ++m) {
                        sum += *reinterpret_cast<const float4*>(&H[HIDX(hcc, hr0 + m + 8, hjj)])
                             - *reinterpret_cast<const float4*>(&H[HIDX(hcc, hr0 + m - 1, hjj)]);
                        *reinterpret_cast<float4*>(&U[UIDX(hcc, hr0 + m, hjj)]) = sum;
                    }
                }
                if (s <= 46 && t >= 160)     // loads for slice s+1 (next A);
                    issue_loads(min(max(zfirst + s + 1, 0), DIM - 1));
                barrier_novm();              // loads stay in flight across this
            }
        }
    }

    // ---- block reduction: wave shuffle, then 4 partials via LDS ----
    __syncthreads();                      // full drain before reuse of LDS
    #pragma unroll
    for (int off = 32; off > 0; off >>= 1)
        acc += __shfl_down(acc, off, 64);
    const int wave = t >> 6;
    if ((t & 63) == 0) wsum[wave] = acc;
    __syncthreads();
    if (t == 0) {
        const float s = wsum[0] + wsum[1] + wsum[2] + wsum[3];
        atomicAdd(out, -s * (1.0f / 8192000.0f));
    }
}

extern "C" void kernel_launch(void* const* d_in, const int* in_sizes, int n_in,
                              void* d_out, int out_size, void* d_ws, size_t ws_size,
                              hipStream_t stream)
{
    const float* x = (const float*)d_in[0];
    const float* y = (const float*)d_in[1];
    float* out = (float*)d_out;

    // d_out is poisoned 0xAA before every call; accumulate atomically on zero
    hipMemsetAsync(out, 0, sizeof(float), stream);

    dim3 grid(DIM / TW, DIM / TH, 2 * (DIM / CD));  // 10 x 10 x 8 = 800 blocks
    lncc_kernel<<<grid, 256, 0, stream>>>(x, y, out);
}